// Round 3
// baseline (434.018 us; speedup 1.0000x reference)
//
#include <hip/hip_runtime.h>
#include <math.h>

#define B_ 4
#define C_ 128
#define HW_ 16384
#define P_ 65536
#define S_ 8388608   // B*C*H*W elements
#define CPG 8        // channels per group (128/16)

typedef unsigned short u16;
typedef __attribute__((ext_vector_type(8))) short short8;
typedef __attribute__((ext_vector_type(4))) float f32x4;

__device__ __forceinline__ float sigmoidf_(float x){ return 1.f/(1.f+__expf(-x)); }
__device__ __forceinline__ float siluf_(float x){ return x*sigmoidf_(x); }
__device__ __forceinline__ u16 f2bf(float f){
  unsigned x = __float_as_uint(f);
  return (u16)((x + 0x7fffu + ((x >> 16) & 1u)) >> 16);
}
__device__ __forceinline__ float b2f(u16 u){ return __uint_as_float(((unsigned)u) << 16); }

// Permute dyn_w rows to interleaved [c*4+f] order (bf16), permute dyn_b,
// convert w_gate/w_out to bf16, zero stats.
__global__ __launch_bounds__(256) void prep_kernel(const float* __restrict__ dyn_w,
    const float* __restrict__ dyn_b, const float* __restrict__ w_gate,
    const float* __restrict__ w_out, u16* __restrict__ wpermb,
    float* __restrict__ bperm, u16* __restrict__ wgbf, u16* __restrict__ wobf,
    float* __restrict__ stats)
{
  int idx = blockIdx.x*256 + threadIdx.x;
  if (idx < 262144) {
    int k = idx & 127, op = (idx >> 7) & 511, d = idx >> 16;
    int c = op >> 2, f = op & 3;
    wpermb[idx] = f2bf(dyn_w[(size_t)((d*512) + (f*128 + c))*128 + k]);
  } else if (idx < 264192) {
    int i2 = idx - 262144;
    int op = i2 & 511, d = i2 >> 9;
    bperm[i2] = dyn_b[d*512 + (op & 3)*128 + (op >> 2)];
  } else if (idx < 280576) {
    int i2 = idx - 264192;
    wgbf[i2] = f2bf(w_gate[i2]);
  } else if (idx < 296960) {
    int i2 = idx - 280576;
    wobf[i2] = f2bf(w_out[i2]);
  } else if (idx < 297216) {
    stats[idx - 296960] = 0.f;
  }
}

// in_proj: X channels-first [128][16384] per batch, W [128][128], out channels-last fp32.
__global__ __launch_bounds__(256) void gemm_inproj(const float* __restrict__ Xall,
    const float* __restrict__ Wm, float* __restrict__ Out)
{
  __shared__ __align__(16) float Xs[16][64];
  __shared__ __align__(16) float Ws[16][64];
  int b = blockIdx.z;
  const float* X = Xall + ((size_t)b << 21);
  float* Ob = Out + ((size_t)b << 21);
  int ot = blockIdx.x << 6, pt = blockIdx.y << 6;
  int t = threadIdx.x, tx = t & 15, ty = t >> 4;
  int kkl = t >> 4, pi = (t & 15) << 2;
  int r = t >> 2, c4 = (t & 3) << 2;
  float acc[4][4] = {};
  for (int k0 = 0; k0 < 128; k0 += 16) {
    float4 xv = *(const float4*)(X + (size_t)(k0 + kkl)*HW_ + pt + pi);
    float4 wv = *(const float4*)(Wm + ((size_t)(ot + r) << 7) + k0 + c4);
    __syncthreads();
    *(float4*)&Xs[kkl][pi] = xv;
    Ws[c4+0][r]=wv.x; Ws[c4+1][r]=wv.y; Ws[c4+2][r]=wv.z; Ws[c4+3][r]=wv.w;
    __syncthreads();
    #pragma unroll
    for (int kk = 0; kk < 16; ++kk) {
      const float4 a = *(const float4*)&Xs[kk][tx << 2];
      const float4 w4 = *(const float4*)&Ws[kk][ty << 2];
      acc[0][0]+=a.x*w4.x; acc[0][1]+=a.x*w4.y; acc[0][2]+=a.x*w4.z; acc[0][3]+=a.x*w4.w;
      acc[1][0]+=a.y*w4.x; acc[1][1]+=a.y*w4.y; acc[1][2]+=a.y*w4.z; acc[1][3]+=a.y*w4.w;
      acc[2][0]+=a.z*w4.x; acc[2][1]+=a.z*w4.y; acc[2][2]+=a.z*w4.z; acc[2][3]+=a.z*w4.w;
      acc[3][0]+=a.w*w4.x; acc[3][1]+=a.w*w4.y; acc[3][2]+=a.w*w4.z; acc[3][3]+=a.w*w4.w;
    }
  }
  int oc = ot + (ty << 2);
  #pragma unroll
  for (int i = 0; i < 4; ++i) {
    float4 o4 = make_float4(acc[i][0], acc[i][1], acc[i][2], acc[i][3]);
    *(float4*)(Ob + ((size_t)(pt + (tx << 2) + i) << 7) + oc) = o4;
  }
}

// MFMA NT GEMM: X bf16 [P][128], W bf16 [OO][128], Out bf16 [P][OO], K=128.
template<int OO, int BIAS, int SIG>
__global__ __launch_bounds__(256) void mfma_nt(const u16* __restrict__ X,
    const u16* __restrict__ Wm, const float* __restrict__ bias, u16* __restrict__ Out)
{
  int wv = threadIdx.x >> 6, lane = threadIdx.x & 63;
  int pt = blockIdx.x*256 + wv*64;
  int ot = blockIdx.y*64;
  int m = lane & 15, kg = lane >> 4;
  short8 Af[4][4];
  #pragma unroll
  for (int rt = 0; rt < 4; ++rt) {
    const u16* ar = X + ((size_t)(pt + rt*16 + m) << 7) + kg*8;
    #pragma unroll
    for (int kk = 0; kk < 4; ++kk)
      Af[rt][kk] = *(const short8*)(ar + kk*32);
  }
  f32x4 acc[4][4];
  #pragma unroll
  for (int rt = 0; rt < 4; ++rt)
    #pragma unroll
    for (int ct = 0; ct < 4; ++ct)
      acc[rt][ct] = (f32x4){0.f, 0.f, 0.f, 0.f};
  #pragma unroll
  for (int ct = 0; ct < 4; ++ct) {
    const u16* wr = Wm + ((size_t)(ot + ct*16 + m) << 7) + kg*8;
    short8 Bf[4];
    #pragma unroll
    for (int kk = 0; kk < 4; ++kk)
      Bf[kk] = *(const short8*)(wr + kk*32);
    #pragma unroll
    for (int rt = 0; rt < 4; ++rt)
      #pragma unroll
      for (int kk = 0; kk < 4; ++kk)
        acc[rt][ct] = __builtin_amdgcn_mfma_f32_16x16x32_bf16(Af[rt][kk], Bf[kk], acc[rt][ct], 0, 0, 0);
  }
  #pragma unroll
  for (int ct = 0; ct < 4; ++ct) {
    float bv = BIAS ? bias[ot + ct*16 + m] : 0.f;
    #pragma unroll
    for (int rt = 0; rt < 4; ++rt) {
      #pragma unroll
      for (int r = 0; r < 4; ++r) {
        int row = pt + rt*16 + kg*4 + r;
        int col = ot + ct*16 + m;
        float v = acc[rt][ct][r] + bv;
        if (SIG) v = sigmoidf_(v);
        Out[(size_t)row*OO + col] = f2bf(v);
      }
    }
  }
}

// Fused coeff-GEMM + bidirectional scan. One block = one line x one 32-ch group.
// AXISW=1: scan along W (dirs lr/rl), PART=0 (store partial).
// AXISW=0: scan along H (dirs tb/bt), PART=1 (add to partial).
template<int AXISW, int PART>
__global__ __launch_bounds__(256) void scan_fused(const u16* __restrict__ Abf,
    const u16* __restrict__ Wd, const float* __restrict__ bias,
    u16* __restrict__ fusedP)
{
  __shared__ __align__(16) u16 xs[128*128];   // 32 KB, swizzled: byte ^ ((pos&7)<<4)
  __shared__ __align__(16) u16 cs[128*256];   // 64 KB coeff, swizzled same
  __shared__ float ys[128*32];                // 16 KB fp32 partial y
  int line = blockIdx.x;
  int b = line >> 7, l = line & 127;
  int c0 = blockIdx.y << 5;
  int t = threadIdx.x;

  // stage xp tile for the line (all 128 input channels)
  #pragma unroll
  for (int i = 0; i < 8; ++i) {
    int idx = i*256 + t;                  // 2048 x 16B chunks
    int pos = idx >> 4, j = idx & 15;
    size_t row = AXISW ? ((size_t)(b<<14) + (l<<7) + pos)
                       : ((size_t)(b<<14) + (pos<<7) + l);
    short8 v = *(const short8*)(Abf + (row<<7) + (j<<3));
    int byte = pos*256 + ((j*16) ^ ((pos&7)<<4));
    *(short8*)((char*)xs + byte) = v;
  }
  __syncthreads();

  // MFMA: coeff[pos][col], col 0..127 = fwd dir (crel*4+f), 128..255 = rev dir.
  // A = W rows (coeff cols), B = xs rows (positions).
  {
    int wv = t >> 6, lane = t & 63;
    int m = lane & 15, kg = lane >> 4;
    int wbase = wv << 6;
    int dir = wbase >> 7;                 // uniform per wave
    const u16* Wdp = Wd + (size_t)dir*65536;
    short8 Afr[4][4];
    #pragma unroll
    for (int ct = 0; ct < 4; ++ct) {
      int col = wbase + ct*16 + m;
      int wrow = (c0 << 2) + (col & 127);
      const u16* wp = Wdp + ((size_t)wrow << 7) + (kg << 3);
      #pragma unroll
      for (int kk = 0; kk < 4; ++kk) Afr[ct][kk] = *(const short8*)(wp + kk*32);
    }
    #pragma unroll 2
    for (int rt = 0; rt < 8; ++rt) {
      int pos = rt*16 + m;
      int sw = (pos & 7) << 4;
      short8 Bfr[4];
      #pragma unroll
      for (int kk = 0; kk < 4; ++kk) {
        int byte = pos*256 + ((kk*64 + kg*16) ^ sw);
        Bfr[kk] = *(const short8*)((char*)xs + byte);
      }
      #pragma unroll
      for (int ct = 0; ct < 4; ++ct) {
        f32x4 acc = (f32x4){0.f,0.f,0.f,0.f};
        #pragma unroll
        for (int kk = 0; kk < 4; ++kk)
          acc = __builtin_amdgcn_mfma_f32_16x16x32_bf16(Afr[ct][kk], Bfr[kk], acc, 0, 0, 0);
        // D: col(=pos)=lane&15, row(=coeff col)=(lane>>4)*4+r
        unsigned lo = ((unsigned)f2bf(acc[0])) | (((unsigned)f2bf(acc[1])) << 16);
        unsigned hi = ((unsigned)f2bf(acc[2])) | (((unsigned)f2bf(acc[3])) << 16);
        int ocol2 = (wbase + ct*16 + (kg << 2)) << 1;
        int byte = pos*512 + (ocol2 ^ sw);
        *(uint2*)((char*)cs + byte) = make_uint2(lo, hi);
      }
    }
  }
  __syncthreads();

  // Scan: lanes 0..31 fwd, 32..63 rev (wave 0 only).
  int crel = t & 31, d = (t >> 5) & 1;
  float4 bv;
  float h = 0.f;
  int colbyte = 0, xbyte = 0;
  if (t < 64) {
    bv = *(const float4*)(bias + (d << 9) + ((c0 + crel) << 2));
    colbyte = (d*256) + (crel << 3);
    xbyte = (c0 + crel) << 1;
    #pragma unroll 4
    for (int s = 0; s < 64; ++s) {
      int pos = d ? (127 - s) : s;
      int sw = (pos & 7) << 4;
      uint2 cw = *(const uint2*)((char*)cs + pos*512 + (colbyte ^ sw));
      float ar = b2f((u16)(cw.x & 0xffff)) + bv.x;
      float br = b2f((u16)(cw.x >> 16)) + bv.y;
      float cr = b2f((u16)(cw.y & 0xffff)) + bv.z;
      float dr = b2f((u16)(cw.y >> 16)) + bv.w;
      float x = b2f(*(const u16*)((char*)xs + pos*256 + (xbyte ^ sw)));
      float a = sigmoidf_(ar);
      h = a*h + br*x;
      float y = cr*h + dr*x;
      ys[pos*32 + crel] = 0.25f*y;        // first visitor stores
    }
  }
  __syncthreads();  // rev's first-half writes visible to fwd's second half (and vice versa)
  if (t < 64) {
    #pragma unroll 4
    for (int s = 64; s < 128; ++s) {
      int pos = d ? (127 - s) : s;
      int sw = (pos & 7) << 4;
      uint2 cw = *(const uint2*)((char*)cs + pos*512 + (colbyte ^ sw));
      float ar = b2f((u16)(cw.x & 0xffff)) + bv.x;
      float br = b2f((u16)(cw.x >> 16)) + bv.y;
      float cr = b2f((u16)(cw.y & 0xffff)) + bv.z;
      float dr = b2f((u16)(cw.y >> 16)) + bv.w;
      float x = b2f(*(const u16*)((char*)xs + pos*256 + (xbyte ^ sw)));
      float a = sigmoidf_(ar);
      h = a*h + br*x;
      float y = cr*h + dr*x;
      ys[pos*32 + crel] += 0.25f*y;       // second visitor accumulates
    }
  }
  __syncthreads();

  // Cooperative write-out: 128 pos x 32 ch, 16 ch per thread.
  {
    int pos = t >> 1, seg = (t & 1) << 4;
    size_t row = AXISW ? ((size_t)(b<<14) + (l<<7) + pos)
                       : ((size_t)(b<<14) + (pos<<7) + l);
    u16* outp = fusedP + (row << 7) + c0 + seg;
    float v[16];
    #pragma unroll
    for (int i = 0; i < 16; ++i) v[i] = ys[pos*32 + seg + i];
    if (PART) {
      short8 o0 = *(const short8*)(outp);
      short8 o1 = *(const short8*)(outp + 8);
      #pragma unroll
      for (int i = 0; i < 8; ++i) { v[i] += b2f((u16)o0[i]); v[8+i] += b2f((u16)o1[i]); }
    }
    short8 r0, r1;
    #pragma unroll
    for (int i = 0; i < 8; ++i) { r0[i] = (short)f2bf(v[i]); r1[i] = (short)f2bf(v[8+i]); }
    *(short8*)(outp) = r0;
    *(short8*)(outp + 8) = r1;
  }
}

// GroupNorm stats over fp32 channels-last.
__global__ __launch_bounds__(256) void gn_stats(const float* __restrict__ X,
    float* __restrict__ stats)
{
  int bg = blockIdx.x, chunk = blockIdx.y;
  int b = bg >> 4, g = bg & 15;
  int t = threadIdx.x;
  int c = t & 7, pr = t >> 3;
  const float* base = X + ((size_t)b << 21) + (g << 3) + c;
  int p0 = chunk << 10;
  float s = 0.f, s2 = 0.f;
  for (int i = 0; i < 32; ++i) {
    float v = base[(size_t)(p0 + (i << 5) + pr) << 7];
    s += v; s2 += v*v;
  }
  #pragma unroll
  for (int off = 32; off; off >>= 1) { s += __shfl_down(s, off); s2 += __shfl_down(s2, off); }
  __shared__ float ls[8];
  int wv = t >> 6, lane = t & 63;
  if (lane == 0) { ls[wv] = s; ls[4 + wv] = s2; }
  __syncthreads();
  if (t == 0) {
    atomicAdd(&stats[bg], ls[0]+ls[1]+ls[2]+ls[3]);
    atomicAdd(&stats[64+bg], ls[4]+ls[5]+ls[6]+ls[7]);
  }
}

// GroupNorm stats over bf16 channels-last.
__global__ __launch_bounds__(256) void gn_stats_bf(const u16* __restrict__ X,
    float* __restrict__ stats)
{
  int bg = blockIdx.x, chunk = blockIdx.y;
  int b = bg >> 4, g = bg & 15;
  int t = threadIdx.x;
  int c = t & 7, pr = t >> 3;
  const u16* base = X + ((size_t)b << 21) + (g << 3) + c;
  int p0 = chunk << 10;
  float s = 0.f, s2 = 0.f;
  for (int i = 0; i < 32; ++i) {
    float v = b2f(base[(size_t)(p0 + (i << 5) + pr) << 7]);
    s += v; s2 += v*v;
  }
  #pragma unroll
  for (int off = 32; off; off >>= 1) { s += __shfl_down(s, off); s2 += __shfl_down(s2, off); }
  __shared__ float ls[8];
  int wv = t >> 6, lane = t & 63;
  if (lane == 0) { ls[wv] = s; ls[4 + wv] = s2; }
  __syncthreads();
  if (t == 0) {
    atomicAdd(&stats[bg], ls[0]+ls[1]+ls[2]+ls[3]);
    atomicAdd(&stats[64+bg], ls[4]+ls[5]+ls[6]+ls[7]);
  }
}

// Apply GN1 + SiLU: read fp32, write bf16.
__global__ __launch_bounds__(256) void gn_apply(const float* __restrict__ X,
    const float* __restrict__ stats, const float* __restrict__ gamma,
    const float* __restrict__ beta, u16* __restrict__ Xb)
{
  int i4 = blockIdx.x*256 + threadIdx.x;
  size_t base = (size_t)i4 << 2;
  int c4 = (int)(base & 127);
  size_t p = base >> 7;
  int b = (int)(p >> 14);
  int g = c4 >> 3;
  const float cnt = (float)(CPG*HW_);
  float mu = stats[b*16+g]/cnt;
  float var = stats[64+b*16+g]/cnt - mu*mu;
  float rs = rsqrtf(var + 1e-5f);
  float4 v = *(const float4*)(X + base);
  ushort4 o;
  o.x = f2bf(siluf_((v.x-mu)*rs*gamma[c4+0]+beta[c4+0]));
  o.y = f2bf(siluf_((v.y-mu)*rs*gamma[c4+1]+beta[c4+1]));
  o.z = f2bf(siluf_((v.z-mu)*rs*gamma[c4+2]+beta[c4+2]));
  o.w = f2bf(siluf_((v.w-mu)*rs*gamma[c4+3]+beta[c4+3]));
  *(ushort4*)(Xb + base) = o;
}

// Depthwise 3x3 with fused gate multiply: z = dw3x3(fused * gate), bf16 in/out.
__global__ __launch_bounds__(256) void dwconv(const u16* __restrict__ Z,
    const u16* __restrict__ G, const float* __restrict__ K9, u16* __restrict__ Outp)
{
  __shared__ float kk[1152];
  int t = threadIdx.x;
  for (int i = t; i < 1152; i += 256) kk[i] = K9[i];
  __syncthreads();
  int i4 = blockIdx.x*256 + t;
  size_t base = (size_t)i4 << 2;
  int c0 = (int)(base & 127);
  size_t p = base >> 7;
  int w = (int)(p & 127), h = (int)((p >> 7) & 127), b = (int)(p >> 14);
  float4 acc = make_float4(0.f,0.f,0.f,0.f);
  #pragma unroll
  for (int di = 0; di < 3; ++di) {
    int hy = h + di - 1;
    if ((unsigned)hy > 127u) continue;
    #pragma unroll
    for (int dj = 0; dj < 3; ++dj) {
      int wx = w + dj - 1;
      if ((unsigned)wx > 127u) continue;
      size_t p2 = ((size_t)b << 14) + (hy << 7) + wx;
      ushort4 zv = *(const ushort4*)(Z + (p2 << 7) + c0);
      ushort4 gv = *(const ushort4*)(G + (p2 << 7) + c0);
      int o = di*3 + dj;
      acc.x += b2f(zv.x) * b2f(gv.x) * kk[c0*9 + o];
      acc.y += b2f(zv.y) * b2f(gv.y) * kk[(c0+1)*9 + o];
      acc.z += b2f(zv.z) * b2f(gv.z) * kk[(c0+2)*9 + o];
      acc.w += b2f(zv.w) * b2f(gv.w) * kk[(c0+3)*9 + o];
    }
  }
  ushort4 ov;
  ov.x = f2bf(acc.x); ov.y = f2bf(acc.y); ov.z = f2bf(acc.z); ov.w = f2bf(acc.w);
  *(ushort4*)(Outp + base) = ov;
}

// GN2 apply + SiLU + transpose to channels-first fp32 output. Input bf16.
__global__ __launch_bounds__(256) void gn_final(const u16* __restrict__ Z,
    const float* __restrict__ stats, const float* __restrict__ gamma,
    const float* __restrict__ beta, float* __restrict__ out)
{
  __shared__ float ls[32][129];
  int w0 = blockIdx.x << 5, hh = blockIdx.y, b = blockIdx.z;
  size_t p0 = ((size_t)b << 14) + (hh << 7) + w0;
  int t = threadIdx.x;
  const float cnt = (float)(CPG*HW_);
  #pragma unroll
  for (int i = 0; i < 4; ++i) {
    int l = t + i*256;
    int row = l >> 5, c4 = (l & 31) << 2;
    ushort4 v = *(const ushort4*)(Z + ((p0 + row) << 7) + c4);
    int g = c4 >> 3;
    float mu = stats[b*16+g]/cnt;
    float var = stats[64+b*16+g]/cnt - mu*mu;
    float rs = rsqrtf(var + 1e-5f);
    float vals[4] = {b2f(v.x), b2f(v.y), b2f(v.z), b2f(v.w)};
    #pragma unroll
    for (int j = 0; j < 4; ++j) {
      float nv = (vals[j]-mu)*rs*gamma[c4+j] + beta[c4+j];
      ls[row][c4+j] = siluf_(nv);
    }
  }
  __syncthreads();
  int ww = t & 31, c0 = t >> 5;
  #pragma unroll
  for (int cc = c0; cc < 128; cc += 8) {
    out[(((size_t)(b*128 + cc)) << 14) + (hh << 7) + (w0 + ww)] = ls[ww][cc];
  }
}

extern "C" void kernel_launch(void* const* d_in, const int* in_sizes, int n_in,
                              void* d_out, int out_size, void* d_ws, size_t ws_size,
                              hipStream_t stream)
{
  (void)in_sizes; (void)n_in; (void)out_size; (void)ws_size;
  const float* x      = (const float*)d_in[0];
  const float* w_in   = (const float*)d_in[1];
  const float* g1g    = (const float*)d_in[2];
  const float* g1b    = (const float*)d_in[3];
  const float* w_gate = (const float*)d_in[4];
  const float* b_gate = (const float*)d_in[5];
  const float* dyn_w  = (const float*)d_in[6];
  const float* dyn_b  = (const float*)d_in[7];
  const float* dwk    = (const float*)d_in[8];
  const float* w_out  = (const float*)d_in[9];
  const float* g2g    = (const float*)d_in[10];
  const float* g2b    = (const float*)d_in[11];
  float* out = (float*)d_out;

  char* p = (char*)d_ws;
  float* A      = (float*)p;            p += (size_t)S_*4;   // xp_raw fp32; later Zdw/Zout bf16
  u16*   Abf    = (u16*)p;              p += (size_t)S_*2;   // xp bf16
  u16*   fusedP = (u16*)p;              p += (size_t)S_*2;   // fused partial/final bf16
  u16*   Gbf    = (u16*)p;              p += (size_t)S_*2;   // gate bf16
  u16*   wpermb = (u16*)p;              p += (size_t)262144*2;
  u16*   wgbf   = (u16*)p;              p += (size_t)16384*2;
  u16*   wobf   = (u16*)p;              p += (size_t)16384*2;
  float* bperm  = (float*)p;            p += (size_t)2048*4;
  float* stats  = (float*)p;            p += (size_t)256*4;
  u16*   Zdw    = (u16*)A;              // aliases A (dead after gn_apply)
  u16*   Zout   = (u16*)A + S_;

  prep_kernel<<<1161, 256, 0, stream>>>(dyn_w, dyn_b, w_gate, w_out,
                                        wpermb, bperm, wgbf, wobf, stats);
  gemm_inproj<<<dim3(2, 256, 4), 256, 0, stream>>>(x, w_in, A);
  gn_stats<<<dim3(64, 16), 256, 0, stream>>>(A, stats);
  gn_apply<<<8192, 256, 0, stream>>>(A, stats, g1g, g1b, Abf);

  scan_fused<1,0><<<dim3(512, 4), 256, 0, stream>>>(Abf, wpermb, bperm, fusedP);
  scan_fused<0,1><<<dim3(512, 4), 256, 0, stream>>>(Abf, wpermb + 2*65536, bperm + 1024, fusedP);

  mfma_nt<128,1,1><<<dim3(256, 2), 256, 0, stream>>>(Abf, wgbf, b_gate, Gbf);
  dwconv<<<8192, 256, 0, stream>>>(fusedP, Gbf, dwk, Zdw);
  mfma_nt<128,0,0><<<dim3(256, 2), 256, 0, stream>>>(Zdw, wobf, nullptr, Zout);
  gn_stats_bf<<<dim3(64, 16), 256, 0, stream>>>(Zout, stats + 128);
  gn_final<<<dim3(4, 128, 4), 256, 0, stream>>>(Zout, stats + 128, g2g, g2b, out);
}

// Round 4
// 290.177 us; speedup vs baseline: 1.4957x; 1.4957x over previous
//
#include <hip/hip_runtime.h>
#include <math.h>

#define B_ 4
#define C_ 128
#define HW_ 16384
#define P_ 65536
#define S_ 8388608   // B*C*H*W elements
#define CPG 8        // channels per group (128/16)

typedef unsigned short u16;
typedef __attribute__((ext_vector_type(8))) short short8;
typedef __attribute__((ext_vector_type(4))) float f32x4;

__device__ __forceinline__ float sigmoidf_(float x){ return 1.f/(1.f+__expf(-x)); }
__device__ __forceinline__ float siluf_(float x){ return x*sigmoidf_(x); }
__device__ __forceinline__ u16 f2bf(float f){
  unsigned x = __float_as_uint(f);
  return (u16)((x + 0x7fffu + ((x >> 16) & 1u)) >> 16);
}
__device__ __forceinline__ float b2f(u16 u){ return __uint_as_float(((unsigned)u) << 16); }

// Build wfrag: dyn_w in MFMA A-fragment order, bf16:
//   wfrag[(((d*32+ct)*4+kk)*64 + lane)*8 + e] = W_d[col=ct*16+(lane&15)][k=kk*32+(lane>>4)*8+e]
// where col = c*4+f maps to dyn_w row f*128+c. Also bperm, wgbf, wobf, stats.
__global__ __launch_bounds__(256) void prep_kernel(const float* __restrict__ dyn_w,
    const float* __restrict__ dyn_b, const float* __restrict__ w_gate,
    const float* __restrict__ w_out, u16* __restrict__ wfrag,
    float* __restrict__ bperm, u16* __restrict__ wgbf, u16* __restrict__ wobf,
    float* __restrict__ stats)
{
  int idx = blockIdx.x*256 + threadIdx.x;
  if (idx < 262144) {
    int e = idx & 7, lane = (idx >> 3) & 63, kk = (idx >> 9) & 3;
    int ct = (idx >> 11) & 31, d = idx >> 16;
    int m = lane & 15, kg = lane >> 4;
    int col = ct*16 + m;
    int c = col >> 2, f = col & 3;
    int k = kk*32 + kg*8 + e;
    wfrag[idx] = f2bf(dyn_w[(size_t)((d*512) + f*128 + c)*128 + k]);
  } else if (idx < 264192) {
    int i2 = idx - 262144;
    int op = i2 & 511, d = i2 >> 9;
    bperm[i2] = dyn_b[d*512 + (op & 3)*128 + (op >> 2)];
  } else if (idx < 280576) {
    int i2 = idx - 264192;
    wgbf[i2] = f2bf(w_gate[i2]);
  } else if (idx < 296960) {
    int i2 = idx - 280576;
    wobf[i2] = f2bf(w_out[i2]);
  } else if (idx < 297216) {
    stats[idx - 296960] = 0.f;
  }
}

// in_proj: X channels-first [128][16384] per batch, W [128][128], out channels-last fp32.
__global__ __launch_bounds__(256) void gemm_inproj(const float* __restrict__ Xall,
    const float* __restrict__ Wm, float* __restrict__ Out)
{
  __shared__ __align__(16) float Xs[16][64];
  __shared__ __align__(16) float Ws[16][64];
  int b = blockIdx.z;
  const float* X = Xall + ((size_t)b << 21);
  float* Ob = Out + ((size_t)b << 21);
  int ot = blockIdx.x << 6, pt = blockIdx.y << 6;
  int t = threadIdx.x, tx = t & 15, ty = t >> 4;
  int kkl = t >> 4, pi = (t & 15) << 2;
  int r = t >> 2, c4 = (t & 3) << 2;
  float acc[4][4] = {};
  for (int k0 = 0; k0 < 128; k0 += 16) {
    float4 xv = *(const float4*)(X + (size_t)(k0 + kkl)*HW_ + pt + pi);
    float4 wv = *(const float4*)(Wm + ((size_t)(ot + r) << 7) + k0 + c4);
    __syncthreads();
    *(float4*)&Xs[kkl][pi] = xv;
    Ws[c4+0][r]=wv.x; Ws[c4+1][r]=wv.y; Ws[c4+2][r]=wv.z; Ws[c4+3][r]=wv.w;
    __syncthreads();
    #pragma unroll
    for (int kk = 0; kk < 16; ++kk) {
      const float4 a = *(const float4*)&Xs[kk][tx << 2];
      const float4 w4 = *(const float4*)&Ws[kk][ty << 2];
      acc[0][0]+=a.x*w4.x; acc[0][1]+=a.x*w4.y; acc[0][2]+=a.x*w4.z; acc[0][3]+=a.x*w4.w;
      acc[1][0]+=a.y*w4.x; acc[1][1]+=a.y*w4.y; acc[1][2]+=a.y*w4.z; acc[1][3]+=a.y*w4.w;
      acc[2][0]+=a.z*w4.x; acc[2][1]+=a.z*w4.y; acc[2][2]+=a.z*w4.z; acc[2][3]+=a.z*w4.w;
      acc[3][0]+=a.w*w4.x; acc[3][1]+=a.w*w4.y; acc[3][2]+=a.w*w4.z; acc[3][3]+=a.w*w4.w;
    }
  }
  int oc = ot + (ty << 2);
  #pragma unroll
  for (int i = 0; i < 4; ++i) {
    float4 o4 = make_float4(acc[i][0], acc[i][1], acc[i][2], acc[i][3]);
    *(float4*)(Ob + ((size_t)(pt + (tx << 2) + i) << 7) + oc) = o4;
  }
}

// MFMA NT GEMM: X bf16 [P][128], W bf16 [OO][128], Out bf16 [P][OO], K=128.
template<int OO, int BIAS, int SIG>
__global__ __launch_bounds__(256) void mfma_nt(const u16* __restrict__ X,
    const u16* __restrict__ Wm, const float* __restrict__ bias, u16* __restrict__ Out)
{
  int wv = threadIdx.x >> 6, lane = threadIdx.x & 63;
  int pt = blockIdx.x*256 + wv*64;
  int ot = blockIdx.y*64;
  int m = lane & 15, kg = lane >> 4;
  short8 Af[4][4];
  #pragma unroll
  for (int rt = 0; rt < 4; ++rt) {
    const u16* ar = X + ((size_t)(pt + rt*16 + m) << 7) + kg*8;
    #pragma unroll
    for (int kk = 0; kk < 4; ++kk)
      Af[rt][kk] = *(const short8*)(ar + kk*32);
  }
  f32x4 acc[4][4];
  #pragma unroll
  for (int rt = 0; rt < 4; ++rt)
    #pragma unroll
    for (int ct = 0; ct < 4; ++ct)
      acc[rt][ct] = (f32x4){0.f, 0.f, 0.f, 0.f};
  #pragma unroll
  for (int ct = 0; ct < 4; ++ct) {
    const u16* wr = Wm + ((size_t)(ot + ct*16 + m) << 7) + kg*8;
    short8 Bf[4];
    #pragma unroll
    for (int kk = 0; kk < 4; ++kk)
      Bf[kk] = *(const short8*)(wr + kk*32);
    #pragma unroll
    for (int rt = 0; rt < 4; ++rt)
      #pragma unroll
      for (int kk = 0; kk < 4; ++kk)
        acc[rt][ct] = __builtin_amdgcn_mfma_f32_16x16x32_bf16(Af[rt][kk], Bf[kk], acc[rt][ct], 0, 0, 0);
  }
  #pragma unroll
  for (int ct = 0; ct < 4; ++ct) {
    float bv = BIAS ? bias[ot + ct*16 + m] : 0.f;
    #pragma unroll
    for (int rt = 0; rt < 4; ++rt) {
      #pragma unroll
      for (int r = 0; r < 4; ++r) {
        int row = pt + rt*16 + kg*4 + r;
        int col = ot + ct*16 + m;
        float v = acc[rt][ct][r] + bv;
        if (SIG) v = sigmoidf_(v);
        Out[(size_t)row*OO + col] = f2bf(v);
      }
    }
  }
}

// Fused coeff-GEMM + bidirectional scan. One block = one full line (128 ch, 2 dirs).
// Waves 0,1 produce fwd coeffs for pos-chunk k (ascending); waves 2,3 produce rev
// coeffs for chunk 7-k (descending). All 256 threads scan (thread = ch x dir).
// AXISW=1: lines along W (dirs lr/rl), PART=0 (store). AXISW=0: along H, PART=1 (RMW add).
template<int AXISW, int PART>
__global__ __launch_bounds__(256, 1) void scan_fused(const u16* __restrict__ Abf,
    const u16* __restrict__ Wf, const float* __restrict__ bias,
    u16* __restrict__ fusedP)
{
  __shared__ __align__(16) u16 xs[128*128];     // 32 KB, swizzled byte ^ ((pos&7)<<4)
  __shared__ __align__(16) u16 cs[2*16*512];    // 32 KB: [dir][posL][512 cols]
  __shared__ __align__(16) float ys[128*128];   // 64 KB fp32 partial y
  int line = blockIdx.x;
  int b = line >> 7, l = line & 127;
  int t = threadIdx.x;
  int wv = t >> 6, lane = t & 63;
  int m = lane & 15, kg = lane >> 4;

  // persistent A (W) fragments: 16 col-tiles per wave, coalesced loads
  short8 Af[16][4];
  #pragma unroll
  for (int ti = 0; ti < 16; ++ti)
    #pragma unroll
    for (int kk = 0; kk < 4; ++kk)
      Af[ti][kk] = *(const short8*)(Wf + (size_t)((((wv*16 + ti)*4 + kk) << 6) + lane)*8);

  // stage xp tile for the line (128 pos x 128 ch)
  #pragma unroll
  for (int i = 0; i < 8; ++i) {
    int idx = i*256 + t;
    int pos = idx >> 4, j = idx & 15;
    size_t row = AXISW ? ((size_t)(b<<14) + (l<<7) + pos)
                       : ((size_t)(b<<14) + (pos<<7) + l);
    short8 v = *(const short8*)(Abf + (row<<7) + (j<<3));
    int byte = pos*256 + ((j*16) ^ ((pos&7)<<4));
    *(short8*)((char*)xs + byte) = v;
  }
  __syncthreads();

  int sd = t >> 7;          // scan dir: 0 fwd, 1 rev (wave-uniform)
  int sc = t & 127;         // scan channel
  float4 bv = *(const float4*)(bias + (sd << 9) + (sc << 2));
  float h = 0.f;

  #pragma unroll 1
  for (int k = 0; k < 8; ++k) {
    // ---- produce coeffs for this phase's chunks
    {
      int pt16 = (wv < 2) ? (k << 4) : ((7 - k) << 4);
      short8 Bfr[4];
      #pragma unroll
      for (int kk = 0; kk < 4; ++kk) {
        int pos = pt16 + m;
        int byte = pos*256 + (((kk << 6) + (kg << 4)) ^ ((pos & 7) << 4));
        Bfr[kk] = *(const short8*)((char*)xs + byte);
      }
      #pragma unroll
      for (int g = 0; g < 4; ++g) {
        f32x4 acc[4];
        #pragma unroll
        for (int j = 0; j < 4; ++j) acc[j] = (f32x4){0.f,0.f,0.f,0.f};
        #pragma unroll
        for (int kk = 0; kk < 4; ++kk)
          #pragma unroll
          for (int j = 0; j < 4; ++j)
            acc[j] = __builtin_amdgcn_mfma_f32_16x16x32_bf16(Af[g*4+j][kk], Bfr[kk], acc[j], 0, 0, 0);
        #pragma unroll
        for (int j = 0; j < 4; ++j) {
          int ctg = wv*16 + g*4 + j;
          int dh = ctg >> 5;
          int colL = ((ctg & 31) << 4) + (kg << 2);
          unsigned lo = ((unsigned)f2bf(acc[j][0])) | (((unsigned)f2bf(acc[j][1])) << 16);
          unsigned hi = ((unsigned)f2bf(acc[j][2])) | (((unsigned)f2bf(acc[j][3])) << 16);
          int byte = (dh << 14) + (m << 10) + (((colL << 1)) ^ ((m & 7) << 4));
          *(uint2*)((char*)cs + byte) = make_uint2(lo, hi);
        }
      }
    }
    __syncthreads();
    // ---- scan 16 steps (all 256 threads)
    {
      int chunk = sd ? (7 - k) : k;
      #pragma unroll
      for (int s = 0; s < 16; ++s) {
        int posL = sd ? (15 - s) : s;
        int pos = (chunk << 4) + posL;
        int sw = (posL & 7) << 4;
        uint2 cw = *(const uint2*)((char*)cs + (sd << 14) + (posL << 10) + ((sc << 3) ^ sw));
        float x = b2f(*(const u16*)((char*)xs + pos*256 + ((sc << 1) ^ sw)));
        float ar = b2f((u16)(cw.x & 0xffff)) + bv.x;
        float br = b2f((u16)(cw.x >> 16)) + bv.y;
        float cr = b2f((u16)(cw.y & 0xffff)) + bv.z;
        float dr = b2f((u16)(cw.y >> 16)) + bv.w;
        float a = sigmoidf_(ar);
        h = a*h + br*x;
        float y = cr*h + dr*x;
        float* yp = &ys[(pos << 7) + sc];
        if (k <= 3) *yp = 0.25f*y;      // first visitor (static per phase)
        else        *yp += 0.25f*y;     // second visitor
      }
    }
    __syncthreads();
  }

  // write-out: 4096 float4 slots, conflict-free linear sweep
  #pragma unroll
  for (int r = 0; r < 16; ++r) {
    int fi = r*256 + t;
    int pos = fi >> 5, cg = fi & 31;
    float4 v = *(const float4*)&ys[(pos << 7) + (cg << 2)];
    size_t row = AXISW ? ((size_t)(b<<14) + (l<<7) + pos)
                       : ((size_t)(b<<14) + (pos<<7) + l);
    u16* op = fusedP + (row << 7) + (cg << 2);
    if (PART) {
      ushort4 o = *(const ushort4*)op;
      v.x += b2f(o.x); v.y += b2f(o.y); v.z += b2f(o.z); v.w += b2f(o.w);
    }
    ushort4 ov; ov.x = f2bf(v.x); ov.y = f2bf(v.y); ov.z = f2bf(v.z); ov.w = f2bf(v.w);
    *(ushort4*)op = ov;
  }
}

// GroupNorm stats over fp32 channels-last.
__global__ __launch_bounds__(256) void gn_stats(const float* __restrict__ X,
    float* __restrict__ stats)
{
  int bg = blockIdx.x, chunk = blockIdx.y;
  int b = bg >> 4, g = bg & 15;
  int t = threadIdx.x;
  int c = t & 7, pr = t >> 3;
  const float* base = X + ((size_t)b << 21) + (g << 3) + c;
  int p0 = chunk << 10;
  float s = 0.f, s2 = 0.f;
  for (int i = 0; i < 32; ++i) {
    float v = base[(size_t)(p0 + (i << 5) + pr) << 7];
    s += v; s2 += v*v;
  }
  #pragma unroll
  for (int off = 32; off; off >>= 1) { s += __shfl_down(s, off); s2 += __shfl_down(s2, off); }
  __shared__ float ls[8];
  int wv = t >> 6, lane = t & 63;
  if (lane == 0) { ls[wv] = s; ls[4 + wv] = s2; }
  __syncthreads();
  if (t == 0) {
    atomicAdd(&stats[bg], ls[0]+ls[1]+ls[2]+ls[3]);
    atomicAdd(&stats[64+bg], ls[4]+ls[5]+ls[6]+ls[7]);
  }
}

// GroupNorm stats over bf16 channels-last.
__global__ __launch_bounds__(256) void gn_stats_bf(const u16* __restrict__ X,
    float* __restrict__ stats)
{
  int bg = blockIdx.x, chunk = blockIdx.y;
  int b = bg >> 4, g = bg & 15;
  int t = threadIdx.x;
  int c = t & 7, pr = t >> 3;
  const u16* base = X + ((size_t)b << 21) + (g << 3) + c;
  int p0 = chunk << 10;
  float s = 0.f, s2 = 0.f;
  for (int i = 0; i < 32; ++i) {
    float v = b2f(base[(size_t)(p0 + (i << 5) + pr) << 7]);
    s += v; s2 += v*v;
  }
  #pragma unroll
  for (int off = 32; off; off >>= 1) { s += __shfl_down(s, off); s2 += __shfl_down(s2, off); }
  __shared__ float ls[8];
  int wv = t >> 6, lane = t & 63;
  if (lane == 0) { ls[wv] = s; ls[4 + wv] = s2; }
  __syncthreads();
  if (t == 0) {
    atomicAdd(&stats[bg], ls[0]+ls[1]+ls[2]+ls[3]);
    atomicAdd(&stats[64+bg], ls[4]+ls[5]+ls[6]+ls[7]);
  }
}

// Apply GN1 + SiLU: read fp32, write bf16.
__global__ __launch_bounds__(256) void gn_apply(const float* __restrict__ X,
    const float* __restrict__ stats, const float* __restrict__ gamma,
    const float* __restrict__ beta, u16* __restrict__ Xb)
{
  int i4 = blockIdx.x*256 + threadIdx.x;
  size_t base = (size_t)i4 << 2;
  int c4 = (int)(base & 127);
  size_t p = base >> 7;
  int b = (int)(p >> 14);
  int g = c4 >> 3;
  const float cnt = (float)(CPG*HW_);
  float mu = stats[b*16+g]/cnt;
  float var = stats[64+b*16+g]/cnt - mu*mu;
  float rs = rsqrtf(var + 1e-5f);
  float4 v = *(const float4*)(X + base);
  ushort4 o;
  o.x = f2bf(siluf_((v.x-mu)*rs*gamma[c4+0]+beta[c4+0]));
  o.y = f2bf(siluf_((v.y-mu)*rs*gamma[c4+1]+beta[c4+1]));
  o.z = f2bf(siluf_((v.z-mu)*rs*gamma[c4+2]+beta[c4+2]));
  o.w = f2bf(siluf_((v.w-mu)*rs*gamma[c4+3]+beta[c4+3]));
  *(ushort4*)(Xb + base) = o;
}

// Depthwise 3x3 with fused gate multiply: z = dw3x3(fused * gate), bf16 in/out.
__global__ __launch_bounds__(256) void dwconv(const u16* __restrict__ Z,
    const u16* __restrict__ G, const float* __restrict__ K9, u16* __restrict__ Outp)
{
  __shared__ float kk[1152];
  int t = threadIdx.x;
  for (int i = t; i < 1152; i += 256) kk[i] = K9[i];
  __syncthreads();
  int i4 = blockIdx.x*256 + t;
  size_t base = (size_t)i4 << 2;
  int c0 = (int)(base & 127);
  size_t p = base >> 7;
  int w = (int)(p & 127), h = (int)((p >> 7) & 127), b = (int)(p >> 14);
  float4 acc = make_float4(0.f,0.f,0.f,0.f);
  #pragma unroll
  for (int di = 0; di < 3; ++di) {
    int hy = h + di - 1;
    if ((unsigned)hy > 127u) continue;
    #pragma unroll
    for (int dj = 0; dj < 3; ++dj) {
      int wx = w + dj - 1;
      if ((unsigned)wx > 127u) continue;
      size_t p2 = ((size_t)b << 14) + (hy << 7) + wx;
      ushort4 zv = *(const ushort4*)(Z + (p2 << 7) + c0);
      ushort4 gv = *(const ushort4*)(G + (p2 << 7) + c0);
      int o = di*3 + dj;
      acc.x += b2f(zv.x) * b2f(gv.x) * kk[c0*9 + o];
      acc.y += b2f(zv.y) * b2f(gv.y) * kk[(c0+1)*9 + o];
      acc.z += b2f(zv.z) * b2f(gv.z) * kk[(c0+2)*9 + o];
      acc.w += b2f(zv.w) * b2f(gv.w) * kk[(c0+3)*9 + o];
    }
  }
  ushort4 ov;
  ov.x = f2bf(acc.x); ov.y = f2bf(acc.y); ov.z = f2bf(acc.z); ov.w = f2bf(acc.w);
  *(ushort4*)(Outp + base) = ov;
}

// GN2 apply + SiLU + transpose to channels-first fp32 output. Input bf16.
__global__ __launch_bounds__(256) void gn_final(const u16* __restrict__ Z,
    const float* __restrict__ stats, const float* __restrict__ gamma,
    const float* __restrict__ beta, float* __restrict__ out)
{
  __shared__ float ls[32][129];
  int w0 = blockIdx.x << 5, hh = blockIdx.y, b = blockIdx.z;
  size_t p0 = ((size_t)b << 14) + (hh << 7) + w0;
  int t = threadIdx.x;
  const float cnt = (float)(CPG*HW_);
  #pragma unroll
  for (int i = 0; i < 4; ++i) {
    int l = t + i*256;
    int row = l >> 5, c4 = (l & 31) << 2;
    ushort4 v = *(const ushort4*)(Z + ((p0 + row) << 7) + c4);
    int g = c4 >> 3;
    float mu = stats[b*16+g]/cnt;
    float var = stats[64+b*16+g]/cnt - mu*mu;
    float rs = rsqrtf(var + 1e-5f);
    float vals[4] = {b2f(v.x), b2f(v.y), b2f(v.z), b2f(v.w)};
    #pragma unroll
    for (int j = 0; j < 4; ++j) {
      float nv = (vals[j]-mu)*rs*gamma[c4+j] + beta[c4+j];
      ls[row][c4+j] = siluf_(nv);
    }
  }
  __syncthreads();
  int ww = t & 31, c0 = t >> 5;
  #pragma unroll
  for (int cc = c0; cc < 128; cc += 8) {
    out[(((size_t)(b*128 + cc)) << 14) + (hh << 7) + (w0 + ww)] = ls[ww][cc];
  }
}

extern "C" void kernel_launch(void* const* d_in, const int* in_sizes, int n_in,
                              void* d_out, int out_size, void* d_ws, size_t ws_size,
                              hipStream_t stream)
{
  (void)in_sizes; (void)n_in; (void)out_size; (void)ws_size;
  const float* x      = (const float*)d_in[0];
  const float* w_in   = (const float*)d_in[1];
  const float* g1g    = (const float*)d_in[2];
  const float* g1b    = (const float*)d_in[3];
  const float* w_gate = (const float*)d_in[4];
  const float* b_gate = (const float*)d_in[5];
  const float* dyn_w  = (const float*)d_in[6];
  const float* dyn_b  = (const float*)d_in[7];
  const float* dwk    = (const float*)d_in[8];
  const float* w_out  = (const float*)d_in[9];
  const float* g2g    = (const float*)d_in[10];
  const float* g2b    = (const float*)d_in[11];
  float* out = (float*)d_out;

  char* p = (char*)d_ws;
  float* A      = (float*)p;            p += (size_t)S_*4;   // xp_raw fp32; later Zdw/Zout bf16
  u16*   Abf    = (u16*)p;              p += (size_t)S_*2;   // xp bf16
  u16*   fusedP = (u16*)p;              p += (size_t)S_*2;   // fused partial/final bf16
  u16*   Gbf    = (u16*)p;              p += (size_t)S_*2;   // gate bf16
  u16*   wfrag  = (u16*)p;              p += (size_t)262144*2;
  u16*   wgbf   = (u16*)p;              p += (size_t)16384*2;
  u16*   wobf   = (u16*)p;              p += (size_t)16384*2;
  float* bperm  = (float*)p;            p += (size_t)2048*4;
  float* stats  = (float*)p;            p += (size_t)256*4;
  u16*   Zdw    = (u16*)A;              // aliases A (dead after gn_apply)
  u16*   Zout   = (u16*)A + S_;

  prep_kernel<<<1161, 256, 0, stream>>>(dyn_w, dyn_b, w_gate, w_out,
                                        wfrag, bperm, wgbf, wobf, stats);
  gemm_inproj<<<dim3(2, 256, 4), 256, 0, stream>>>(x, w_in, A);
  gn_stats<<<dim3(64, 16), 256, 0, stream>>>(A, stats);
  gn_apply<<<8192, 256, 0, stream>>>(A, stats, g1g, g1b, Abf);

  scan_fused<1,0><<<512, 256, 0, stream>>>(Abf, wfrag, bperm, fusedP);
  scan_fused<0,1><<<512, 256, 0, stream>>>(Abf, wfrag + 131072, bperm + 1024, fusedP);

  mfma_nt<128,1,1><<<dim3(256, 2), 256, 0, stream>>>(Abf, wgbf, b_gate, Gbf);
  dwconv<<<8192, 256, 0, stream>>>(fusedP, Gbf, dwk, Zdw);
  mfma_nt<128,0,0><<<dim3(256, 2), 256, 0, stream>>>(Zdw, wobf, nullptr, Zout);
  gn_stats_bf<<<dim3(64, 16), 256, 0, stream>>>(Zout, stats + 128);
  gn_final<<<dim3(4, 128, 4), 256, 0, stream>>>(Zout, stats + 128, g2g, g2b, out);
}

// Round 5
// 250.125 us; speedup vs baseline: 1.7352x; 1.1601x over previous
//
#include <hip/hip_runtime.h>
#include <math.h>

#define B_ 4
#define C_ 128
#define HW_ 16384
#define P_ 65536
#define S_ 8388608   // B*C*H*W elements
#define CPG 8        // channels per group (128/16)

typedef unsigned short u16;
typedef __attribute__((ext_vector_type(8))) short short8;
typedef __attribute__((ext_vector_type(4))) float f32x4;

__device__ __forceinline__ float sigmoidf_(float x){ return 1.f/(1.f+__expf(-x)); }
__device__ __forceinline__ float siluf_(float x){ return x*sigmoidf_(x); }
__device__ __forceinline__ u16 f2bf(float f){
  unsigned x = __float_as_uint(f);
  return (u16)((x + 0x7fffu + ((x >> 16) & 1u)) >> 16);
}
__device__ __forceinline__ float b2f(u16 u){ return __uint_as_float(((unsigned)u) << 16); }

// Build wfrag: dyn_w in MFMA A-fragment order, bf16:
//   wfrag[(((d*32+ct)*4+kk)*64 + lane)*8 + e] = W_d[col=ct*16+(lane&15)][k=kk*32+(lane>>4)*8+e]
// where col = c*4+f maps to dyn_w row f*128+c. Also bperm, wgbf, wobf, stats.
__global__ __launch_bounds__(256) void prep_kernel(const float* __restrict__ dyn_w,
    const float* __restrict__ dyn_b, const float* __restrict__ w_gate,
    const float* __restrict__ w_out, u16* __restrict__ wfrag,
    float* __restrict__ bperm, u16* __restrict__ wgbf, u16* __restrict__ wobf,
    float* __restrict__ stats)
{
  int idx = blockIdx.x*256 + threadIdx.x;
  if (idx < 262144) {
    int e = idx & 7, lane = (idx >> 3) & 63, kk = (idx >> 9) & 3;
    int ct = (idx >> 11) & 31, d = idx >> 16;
    int m = lane & 15, kg = lane >> 4;
    int col = ct*16 + m;
    int c = col >> 2, f = col & 3;
    int k = kk*32 + kg*8 + e;
    wfrag[idx] = f2bf(dyn_w[(size_t)((d*512) + f*128 + c)*128 + k]);
  } else if (idx < 264192) {
    int i2 = idx - 262144;
    int op = i2 & 511, d = i2 >> 9;
    bperm[i2] = dyn_b[d*512 + (op & 3)*128 + (op >> 2)];
  } else if (idx < 280576) {
    int i2 = idx - 264192;
    wgbf[i2] = f2bf(w_gate[i2]);
  } else if (idx < 296960) {
    int i2 = idx - 280576;
    wobf[i2] = f2bf(w_out[i2]);
  } else if (idx < 297216) {
    stats[idx - 296960] = 0.f;
  }
}

// in_proj: X channels-first [128][16384] per batch, W [128][128], out channels-last fp32.
__global__ __launch_bounds__(256) void gemm_inproj(const float* __restrict__ Xall,
    const float* __restrict__ Wm, float* __restrict__ Out)
{
  __shared__ __align__(16) float Xs[16][64];
  __shared__ __align__(16) float Ws[16][64];
  int b = blockIdx.z;
  const float* X = Xall + ((size_t)b << 21);
  float* Ob = Out + ((size_t)b << 21);
  int ot = blockIdx.x << 6, pt = blockIdx.y << 6;
  int t = threadIdx.x, tx = t & 15, ty = t >> 4;
  int kkl = t >> 4, pi = (t & 15) << 2;
  int r = t >> 2, c4 = (t & 3) << 2;
  float acc[4][4] = {};
  for (int k0 = 0; k0 < 128; k0 += 16) {
    float4 xv = *(const float4*)(X + (size_t)(k0 + kkl)*HW_ + pt + pi);
    float4 wv = *(const float4*)(Wm + ((size_t)(ot + r) << 7) + k0 + c4);
    __syncthreads();
    *(float4*)&Xs[kkl][pi] = xv;
    Ws[c4+0][r]=wv.x; Ws[c4+1][r]=wv.y; Ws[c4+2][r]=wv.z; Ws[c4+3][r]=wv.w;
    __syncthreads();
    #pragma unroll
    for (int kk = 0; kk < 16; ++kk) {
      const float4 a = *(const float4*)&Xs[kk][tx << 2];
      const float4 w4 = *(const float4*)&Ws[kk][ty << 2];
      acc[0][0]+=a.x*w4.x; acc[0][1]+=a.x*w4.y; acc[0][2]+=a.x*w4.z; acc[0][3]+=a.x*w4.w;
      acc[1][0]+=a.y*w4.x; acc[1][1]+=a.y*w4.y; acc[1][2]+=a.y*w4.z; acc[1][3]+=a.y*w4.w;
      acc[2][0]+=a.z*w4.x; acc[2][1]+=a.z*w4.y; acc[2][2]+=a.z*w4.z; acc[2][3]+=a.z*w4.w;
      acc[3][0]+=a.w*w4.x; acc[3][1]+=a.w*w4.y; acc[3][2]+=a.w*w4.z; acc[3][3]+=a.w*w4.w;
    }
  }
  int oc = ot + (ty << 2);
  #pragma unroll
  for (int i = 0; i < 4; ++i) {
    float4 o4 = make_float4(acc[i][0], acc[i][1], acc[i][2], acc[i][3]);
    *(float4*)(Ob + ((size_t)(pt + (tx << 2) + i) << 7) + oc) = o4;
  }
}

// MFMA NT GEMM: X bf16 [P][128], W bf16 [OO][128], Out bf16 [P][OO], K=128.
template<int OO, int BIAS, int SIG>
__global__ __launch_bounds__(256) void mfma_nt(const u16* __restrict__ X,
    const u16* __restrict__ Wm, const float* __restrict__ bias, u16* __restrict__ Out)
{
  int wv = threadIdx.x >> 6, lane = threadIdx.x & 63;
  int pt = blockIdx.x*256 + wv*64;
  int ot = blockIdx.y*64;
  int m = lane & 15, kg = lane >> 4;
  short8 Af[4][4];
  #pragma unroll
  for (int rt = 0; rt < 4; ++rt) {
    const u16* ar = X + ((size_t)(pt + rt*16 + m) << 7) + kg*8;
    #pragma unroll
    for (int kk = 0; kk < 4; ++kk)
      Af[rt][kk] = *(const short8*)(ar + kk*32);
  }
  f32x4 acc[4][4];
  #pragma unroll
  for (int rt = 0; rt < 4; ++rt)
    #pragma unroll
    for (int ct = 0; ct < 4; ++ct)
      acc[rt][ct] = (f32x4){0.f, 0.f, 0.f, 0.f};
  #pragma unroll
  for (int ct = 0; ct < 4; ++ct) {
    const u16* wr = Wm + ((size_t)(ot + ct*16 + m) << 7) + kg*8;
    short8 Bf[4];
    #pragma unroll
    for (int kk = 0; kk < 4; ++kk)
      Bf[kk] = *(const short8*)(wr + kk*32);
    #pragma unroll
    for (int rt = 0; rt < 4; ++rt)
      #pragma unroll
      for (int kk = 0; kk < 4; ++kk)
        acc[rt][ct] = __builtin_amdgcn_mfma_f32_16x16x32_bf16(Af[rt][kk], Bf[kk], acc[rt][ct], 0, 0, 0);
  }
  #pragma unroll
  for (int ct = 0; ct < 4; ++ct) {
    float bv = BIAS ? bias[ot + ct*16 + m] : 0.f;
    #pragma unroll
    for (int rt = 0; rt < 4; ++rt) {
      #pragma unroll
      for (int r = 0; r < 4; ++r) {
        int row = pt + rt*16 + kg*4 + r;
        int col = ot + ct*16 + m;
        float v = acc[rt][ct][r] + bv;
        if (SIG) v = sigmoidf_(v);
        Out[(size_t)row*OO + col] = f2bf(v);
      }
    }
  }
}

// Produce 16-pos coeff chunk into cs double buffer (bank-swizzled).
#define PRODUCE(NT, bufv, chunkv)  do { \
  int posg_ = (chunkv)*16 + m; int swp_ = (posg_ & 7) << 4; \
  short8 Bfr[4]; \
  _Pragma("unroll") for (int kk = 0; kk < 4; ++kk) \
    Bfr[kk] = *(const short8*)((char*)xs + posg_*256 + (((kk<<6)+(kg<<4)) ^ swp_)); \
  _Pragma("unroll") for (int ti = 0; ti < NT; ++ti) { \
    f32x4 acc = (f32x4){0.f,0.f,0.f,0.f}; \
    _Pragma("unroll") for (int kk = 0; kk < 4; ++kk) \
      acc = __builtin_amdgcn_mfma_f32_16x16x32_bf16(Af[ti][kk], Bfr[kk], acc, 0, 0, 0); \
    int colL_ = (tbase + ti)*16 + (kg<<2); \
    unsigned lo_ = (unsigned)f2bf(acc[0]) | ((unsigned)f2bf(acc[1])<<16); \
    unsigned hi_ = (unsigned)f2bf(acc[2]) | ((unsigned)f2bf(acc[3])<<16); \
    int byte_ = (((bufv)*2 + dw)<<14) + (m<<10) + ((colL_<<1) ^ ((m&7)<<4)); \
    *(uint2*)((char*)cs + byte_) = make_uint2(lo_, hi_); \
  } } while(0)

#define SCAN_STEP(s) { \
  float ar = b2f((u16)(cw[s].x & 0xffffu)) + bv.x; \
  float br = b2f((u16)(cw[s].x >> 16)) + bv.y; \
  float cr = b2f((u16)(cw[s].y & 0xffffu)) + bv.z; \
  float dr = b2f((u16)(cw[s].y >> 16)) + bv.w; \
  float aa = sigmoidf_(ar); \
  h = aa*h + br*xf[s]; \
  yv[s] = cr*h + dr*xf[s]; }

// Fused coeff-GEMM + bidirectional scan, wave-specialized, cs double-buffered.
// Block = 512 thr (8 waves): waves 0-3 = scanners + 4 W-tiles each; waves 4-7 =
// producers with 12 W-tiles each. dirs: waves {0,1,4,5} fwd, {2,3,6,7} rev.
// AXISW=1: lines along W (lr/rl), PART=0. AXISW=0: along H (tb/bt), PART=1 (RMW).
template<int AXISW, int PART>
__global__ __launch_bounds__(512, 2) void scan_fused(const u16* __restrict__ Abf,
    const u16* __restrict__ Wf, const float* __restrict__ bias,
    u16* __restrict__ fusedP)
{
  __shared__ __align__(16) u16 xs[128*128];      // 32 KB, swizzled byte ^ ((pos&7)<<4)
  __shared__ __align__(16) u16 cs[2][2][16*512]; // 64 KB: [buf][dir][16 pos][512 cols]
  int line = blockIdx.x;
  int b = line >> 7, l = line & 127;
  int t = threadIdx.x;
  int wv = t >> 6, lane = t & 63;
  int m = lane & 15, kg = lane >> 4;
  int dw = (wv >> 1) & 1;    // this wave's coeff direction

  // stage xp tile for the line (128 pos x 128 ch)
  #pragma unroll
  for (int i = 0; i < 4; ++i) {
    int idx = i*512 + t;
    int pos = idx >> 4, j = idx & 15;
    size_t row = AXISW ? ((size_t)(b<<14) + (l<<7) + pos)
                       : ((size_t)(b<<14) + (pos<<7) + l);
    short8 v = *(const short8*)(Abf + (row<<7) + (j<<3));
    int byte = pos*256 + ((j*16) ^ ((pos&7)<<4));
    *(short8*)((char*)xs + byte) = v;
  }

  if (wv < 4) {
    // ---------- scanner + light producer ----------
    int tbase = (wv & 1) * 4;
    short8 Af[4][4];
    #pragma unroll
    for (int ti = 0; ti < 4; ++ti)
      #pragma unroll
      for (int kk = 0; kk < 4; ++kk)
        Af[ti][kk] = *(const short8*)(Wf + (size_t)(((dw*32 + tbase + ti)*4 + kk)*64 + lane)*8);
    __syncthreads();                       // xs ready
    PRODUCE(4, 0, dw ? 7 : 0);
    __syncthreads();                       // cs[0] ready

    int sd = dw;
    int sc = ((wv & 1) << 6) + lane;       // scan channel 0..127
    float4 bv = *(const float4*)(bias + (sd << 9) + (sc << 2));
    float h = 0.f;

    #pragma unroll 1
    for (int k = 0; k < 8; ++k) {
      if (k < 7) PRODUCE(4, (k+1)&1, dw ? (6-k) : (k+1));
      int chunk = sd ? (7-k) : k;
      int csb = (((k&1)*2 + sd) << 14);
      uint2 cw[16];
      #pragma unroll
      for (int s = 0; s < 16; ++s)
        cw[s] = *(const uint2*)((char*)cs + csb + (s<<10) + ((sc<<3) ^ ((s&7)<<4)));
      float xf[16];
      #pragma unroll
      for (int s = 0; s < 16; ++s) {
        int pos = (chunk<<4) + s;
        xf[s] = b2f(*(const u16*)((char*)xs + pos*256 + ((sc<<1) ^ ((s&7)<<4))));
      }
      int rmw = PART || (k >= 4);          // second visitor (or H-pass) accumulates
      float pv[16];
      if (rmw) {
        #pragma unroll
        for (int s = 0; s < 16; ++s) {
          int pos = (chunk<<4) + s;
          size_t rowg = AXISW ? ((size_t)(b<<14) + (l<<7) + pos)
                              : ((size_t)(b<<14) + (pos<<7) + l);
          pv[s] = b2f(fusedP[(rowg<<7) + sc]);
        }
      }
      float yv[16];
      if (sd == 0) {
        #pragma unroll
        for (int s = 0; s < 16; ++s) SCAN_STEP(s)
      } else {
        #pragma unroll
        for (int s = 15; s >= 0; --s) SCAN_STEP(s)
      }
      #pragma unroll
      for (int s = 0; s < 16; ++s) {
        int pos = (chunk<<4) + s;
        size_t rowg = AXISW ? ((size_t)(b<<14) + (l<<7) + pos)
                            : ((size_t)(b<<14) + (pos<<7) + l);
        float v = 0.25f*yv[s] + (rmw ? pv[s] : 0.f);
        fusedP[(rowg<<7) + sc] = f2bf(v);
      }
      __syncthreads();
    }
  } else {
    // ---------- heavy producer ----------
    int tbase = 8 + (wv & 1) * 12;
    short8 Af[12][4];
    #pragma unroll
    for (int ti = 0; ti < 12; ++ti)
      #pragma unroll
      for (int kk = 0; kk < 4; ++kk)
        Af[ti][kk] = *(const short8*)(Wf + (size_t)(((dw*32 + tbase + ti)*4 + kk)*64 + lane)*8);
    __syncthreads();                       // xs ready
    PRODUCE(12, 0, dw ? 7 : 0);
    __syncthreads();                       // cs[0] ready
    #pragma unroll 1
    for (int k = 0; k < 8; ++k) {
      if (k < 7) PRODUCE(12, (k+1)&1, dw ? (6-k) : (k+1));
      __syncthreads();
    }
  }
}

// GroupNorm stats over fp32 channels-last.
__global__ __launch_bounds__(256) void gn_stats(const float* __restrict__ X,
    float* __restrict__ stats)
{
  int bg = blockIdx.x, chunk = blockIdx.y;
  int b = bg >> 4, g = bg & 15;
  int t = threadIdx.x;
  int c = t & 7, pr = t >> 3;
  const float* base = X + ((size_t)b << 21) + (g << 3) + c;
  int p0 = chunk << 10;
  float s = 0.f, s2 = 0.f;
  for (int i = 0; i < 32; ++i) {
    float v = base[(size_t)(p0 + (i << 5) + pr) << 7];
    s += v; s2 += v*v;
  }
  #pragma unroll
  for (int off = 32; off; off >>= 1) { s += __shfl_down(s, off); s2 += __shfl_down(s2, off); }
  __shared__ float ls[8];
  int wv = t >> 6, lane = t & 63;
  if (lane == 0) { ls[wv] = s; ls[4 + wv] = s2; }
  __syncthreads();
  if (t == 0) {
    atomicAdd(&stats[bg], ls[0]+ls[1]+ls[2]+ls[3]);
    atomicAdd(&stats[64+bg], ls[4]+ls[5]+ls[6]+ls[7]);
  }
}

// GroupNorm stats over bf16 channels-last.
__global__ __launch_bounds__(256) void gn_stats_bf(const u16* __restrict__ X,
    float* __restrict__ stats)
{
  int bg = blockIdx.x, chunk = blockIdx.y;
  int b = bg >> 4, g = bg & 15;
  int t = threadIdx.x;
  int c = t & 7, pr = t >> 3;
  const u16* base = X + ((size_t)b << 21) + (g << 3) + c;
  int p0 = chunk << 10;
  float s = 0.f, s2 = 0.f;
  for (int i = 0; i < 32; ++i) {
    float v = b2f(base[(size_t)(p0 + (i << 5) + pr) << 7]);
    s += v; s2 += v*v;
  }
  #pragma unroll
  for (int off = 32; off; off >>= 1) { s += __shfl_down(s, off); s2 += __shfl_down(s2, off); }
  __shared__ float ls[8];
  int wv = t >> 6, lane = t & 63;
  if (lane == 0) { ls[wv] = s; ls[4 + wv] = s2; }
  __syncthreads();
  if (t == 0) {
    atomicAdd(&stats[bg], ls[0]+ls[1]+ls[2]+ls[3]);
    atomicAdd(&stats[64+bg], ls[4]+ls[5]+ls[6]+ls[7]);
  }
}

// Apply GN1 + SiLU: read fp32, write bf16.
__global__ __launch_bounds__(256) void gn_apply(const float* __restrict__ X,
    const float* __restrict__ stats, const float* __restrict__ gamma,
    const float* __restrict__ beta, u16* __restrict__ Xb)
{
  int i4 = blockIdx.x*256 + threadIdx.x;
  size_t base = (size_t)i4 << 2;
  int c4 = (int)(base & 127);
  size_t p = base >> 7;
  int b = (int)(p >> 14);
  int g = c4 >> 3;
  const float cnt = (float)(CPG*HW_);
  float mu = stats[b*16+g]/cnt;
  float var = stats[64+b*16+g]/cnt - mu*mu;
  float rs = rsqrtf(var + 1e-5f);
  float4 v = *(const float4*)(X + base);
  ushort4 o;
  o.x = f2bf(siluf_((v.x-mu)*rs*gamma[c4+0]+beta[c4+0]));
  o.y = f2bf(siluf_((v.y-mu)*rs*gamma[c4+1]+beta[c4+1]));
  o.z = f2bf(siluf_((v.z-mu)*rs*gamma[c4+2]+beta[c4+2]));
  o.w = f2bf(siluf_((v.w-mu)*rs*gamma[c4+3]+beta[c4+3]));
  *(ushort4*)(Xb + base) = o;
}

// Depthwise 3x3 with fused gate multiply: z = dw3x3(fused * gate), bf16 in/out.
__global__ __launch_bounds__(256) void dwconv(const u16* __restrict__ Z,
    const u16* __restrict__ G, const float* __restrict__ K9, u16* __restrict__ Outp)
{
  __shared__ float kk[1152];
  int t = threadIdx.x;
  for (int i = t; i < 1152; i += 256) kk[i] = K9[i];
  __syncthreads();
  int i4 = blockIdx.x*256 + t;
  size_t base = (size_t)i4 << 2;
  int c0 = (int)(base & 127);
  size_t p = base >> 7;
  int w = (int)(p & 127), h = (int)((p >> 7) & 127), b = (int)(p >> 14);
  float4 acc = make_float4(0.f,0.f,0.f,0.f);
  #pragma unroll
  for (int di = 0; di < 3; ++di) {
    int hy = h + di - 1;
    if ((unsigned)hy > 127u) continue;
    #pragma unroll
    for (int dj = 0; dj < 3; ++dj) {
      int wx = w + dj - 1;
      if ((unsigned)wx > 127u) continue;
      size_t p2 = ((size_t)b << 14) + (hy << 7) + wx;
      ushort4 zv = *(const ushort4*)(Z + (p2 << 7) + c0);
      ushort4 gv = *(const ushort4*)(G + (p2 << 7) + c0);
      int o = di*3 + dj;
      acc.x += b2f(zv.x) * b2f(gv.x) * kk[c0*9 + o];
      acc.y += b2f(zv.y) * b2f(gv.y) * kk[(c0+1)*9 + o];
      acc.z += b2f(zv.z) * b2f(gv.z) * kk[(c0+2)*9 + o];
      acc.w += b2f(zv.w) * b2f(gv.w) * kk[(c0+3)*9 + o];
    }
  }
  ushort4 ov;
  ov.x = f2bf(acc.x); ov.y = f2bf(acc.y); ov.z = f2bf(acc.z); ov.w = f2bf(acc.w);
  *(ushort4*)(Outp + base) = ov;
}

// GN2 apply + SiLU + transpose to channels-first fp32 output. Input bf16.
__global__ __launch_bounds__(256) void gn_final(const u16* __restrict__ Z,
    const float* __restrict__ stats, const float* __restrict__ gamma,
    const float* __restrict__ beta, float* __restrict__ out)
{
  __shared__ float ls[32][129];
  int w0 = blockIdx.x << 5, hh = blockIdx.y, b = blockIdx.z;
  size_t p0 = ((size_t)b << 14) + (hh << 7) + w0;
  int t = threadIdx.x;
  const float cnt = (float)(CPG*HW_);
  #pragma unroll
  for (int i = 0; i < 4; ++i) {
    int l = t + i*256;
    int row = l >> 5, c4 = (l & 31) << 2;
    ushort4 v = *(const ushort4*)(Z + ((p0 + row) << 7) + c4);
    int g = c4 >> 3;
    float mu = stats[b*16+g]/cnt;
    float var = stats[64+b*16+g]/cnt - mu*mu;
    float rs = rsqrtf(var + 1e-5f);
    float vals[4] = {b2f(v.x), b2f(v.y), b2f(v.z), b2f(v.w)};
    #pragma unroll
    for (int j = 0; j < 4; ++j) {
      float nv = (vals[j]-mu)*rs*gamma[c4+j] + beta[c4+j];
      ls[row][c4+j] = siluf_(nv);
    }
  }
  __syncthreads();
  int ww = t & 31, c0 = t >> 5;
  #pragma unroll
  for (int cc = c0; cc < 128; cc += 8) {
    out[(((size_t)(b*128 + cc)) << 14) + (hh << 7) + (w0 + ww)] = ls[ww][cc];
  }
}

extern "C" void kernel_launch(void* const* d_in, const int* in_sizes, int n_in,
                              void* d_out, int out_size, void* d_ws, size_t ws_size,
                              hipStream_t stream)
{
  (void)in_sizes; (void)n_in; (void)out_size; (void)ws_size;
  const float* x      = (const float*)d_in[0];
  const float* w_in   = (const float*)d_in[1];
  const float* g1g    = (const float*)d_in[2];
  const float* g1b    = (const float*)d_in[3];
  const float* w_gate = (const float*)d_in[4];
  const float* b_gate = (const float*)d_in[5];
  const float* dyn_w  = (const float*)d_in[6];
  const float* dyn_b  = (const float*)d_in[7];
  const float* dwk    = (const float*)d_in[8];
  const float* w_out  = (const float*)d_in[9];
  const float* g2g    = (const float*)d_in[10];
  const float* g2b    = (const float*)d_in[11];
  float* out = (float*)d_out;

  char* p = (char*)d_ws;
  float* A      = (float*)p;            p += (size_t)S_*4;   // xp_raw fp32; later Zdw/Zout bf16
  u16*   Abf    = (u16*)p;              p += (size_t)S_*2;   // xp bf16
  u16*   fusedP = (u16*)p;              p += (size_t)S_*2;   // fused partial/final bf16
  u16*   Gbf    = (u16*)p;              p += (size_t)S_*2;   // gate bf16
  u16*   wfrag  = (u16*)p;              p += (size_t)262144*2;
  u16*   wgbf   = (u16*)p;              p += (size_t)16384*2;
  u16*   wobf   = (u16*)p;              p += (size_t)16384*2;
  float* bperm  = (float*)p;            p += (size_t)2048*4;
  float* stats  = (float*)p;            p += (size_t)256*4;
  u16*   Zdw    = (u16*)A;              // aliases A (dead after gn_apply)
  u16*   Zout   = (u16*)A + S_;

  prep_kernel<<<1161, 256, 0, stream>>>(dyn_w, dyn_b, w_gate, w_out,
                                        wfrag, bperm, wgbf, wobf, stats);
  gemm_inproj<<<dim3(2, 256, 4), 256, 0, stream>>>(x, w_in, A);
  gn_stats<<<dim3(64, 16), 256, 0, stream>>>(A, stats);
  gn_apply<<<8192, 256, 0, stream>>>(A, stats, g1g, g1b, Abf);

  scan_fused<1,0><<<512, 512, 0, stream>>>(Abf, wfrag, bperm, fusedP);
  scan_fused<0,1><<<512, 512, 0, stream>>>(Abf, wfrag + 131072, bperm + 1024, fusedP);

  mfma_nt<128,1,1><<<dim3(256, 2), 256, 0, stream>>>(Abf, wgbf, b_gate, Gbf);
  dwconv<<<8192, 256, 0, stream>>>(fusedP, Gbf, dwk, Zdw);
  mfma_nt<128,0,0><<<dim3(256, 2), 256, 0, stream>>>(Zdw, wobf, nullptr, Zout);
  gn_stats_bf<<<dim3(64, 16), 256, 0, stream>>>(Zout, stats + 128);
  gn_final<<<dim3(4, 128, 4), 256, 0, stream>>>(Zout, stats + 128, g2g, g2b, out);
}